// Round 3
// baseline (1729.527 us; speedup 1.0000x reference)
//
#include <hip/hip_runtime.h>
#include <math.h>

constexpr int N = 512;
constexpr int D = 16;
constexpr int E = 12;

// ---- workspace layout (float offsets) ----
// OFF_A:  A -> L panels (Cholesky) -> iK (after SYRK)
// OFF_IK: W = L^{-1}
constexpr size_t OFF_A     = 0;                            // E*N*N
constexpr size_t OFF_IK    = OFF_A    + (size_t)E*N*N;     // E*N*N
constexpr size_t OFF_XS    = OFF_IK   + (size_t)E*N*N;     // N*D
constexpr size_t OFF_INP   = OFF_XS   + (size_t)N*D;       // N*D
constexpr size_t OFF_YN    = OFF_INP  + (size_t)N*D;       // E*N
constexpr size_t OFF_BETA  = OFF_YN   + (size_t)E*N;       // E*N
constexpr size_t OFF_KVEC  = OFF_BETA + (size_t)E*N;       // E*N
constexpr size_t OFF_LB    = OFF_KVEC + (size_t)E*N;       // E*N
constexpr size_t OFF_TIL   = OFF_LB   + (size_t)E*N;       // E*N*D
constexpr size_t OFF_X1    = OFF_TIL  + (size_t)E*N*D;     // E*N*D
constexpr size_t OFF_X1Q   = OFF_X1   + (size_t)E*N*D;     // E*E*N*D
constexpr size_t OFF_XS1   = OFF_X1Q  + (size_t)E*E*N*D;   // E*E*N
constexpr size_t OFF_XS2   = OFF_XS1  + (size_t)E*E*N;     // E*E*N
constexpr size_t OFF_Q     = OFF_XS2  + (size_t)E*E*N;     // E*E*D*D
constexpr size_t OFF_BINV  = OFF_Q    + (size_t)E*E*D*D;   // E*D*D
constexpr size_t OFF_C     = OFF_BINV + (size_t)E*D*D;     // E
constexpr size_t OFF_ISDR  = OFF_C    + E;                 // E*E
constexpr size_t OFF_SPART = OFF_ISDR + E*E;               // E*E*32
constexpr size_t OFF_TPART = OFF_SPART+ (size_t)E*E*32;    // E*32
constexpr size_t OFF_XMEAN = OFF_TPART+ (size_t)E*32;      // D
constexpr size_t OFF_XSTD  = OFF_XMEAN+ D;                 // D
constexpr size_t OFF_YMEAN = OFF_XSTD + D;                 // E
constexpr size_t OFF_YSTD  = OFF_YMEAN+ E;                 // E
constexpr size_t OFF_SSM   = OFF_YSTD + E;                 // D*D

// ---------- 1. standardization (wave-shuffle reductions, few barriers) ----------
__global__ __launch_bounds__(512) void k_prep(const float* __restrict__ X, const float* __restrict__ Y,
                                              const float* __restrict__ m, const float* __restrict__ s,
                                              float* __restrict__ ws) {
    int tid = threadIdx.x;
    int lane = tid & 63, wave = tid >> 6;   // 8 waves
    __shared__ float meanX[D], stdX[D], meanY[E], stdY[E], mmsh[D];

    for (int col = wave; col < D + E; col += 8) {
        float s1 = 0.f, s2 = 0.f;
        if (col < D) {
            #pragma unroll
            for (int i = 0; i < 8; ++i) { float v = X[(i*64 + lane)*D + col]; s1 += v; s2 += v*v; }
        } else {
            int e = col - D;
            #pragma unroll
            for (int i = 0; i < 8; ++i) { float v = Y[(i*64 + lane)*E + e]; s1 += v; s2 += v*v; }
        }
        #pragma unroll
        for (int off = 32; off > 0; off >>= 1) { s1 += __shfl_xor(s1, off); s2 += __shfl_xor(s2, off); }
        if (lane == 0) {
            float mean = s1 * (1.0f/N);
            float var  = (s2 - (float)N*mean*mean) * (1.0f/(N-1));
            float sd   = sqrtf(var);
            if (col < D) { meanX[col] = mean; stdX[col] = sd; }
            else         { meanY[col-D] = mean; stdY[col-D] = sd; }
        }
    }
    __syncthreads();
    if (tid < D) {
        mmsh[tid] = (m[tid] - meanX[tid]) / stdX[tid];
        ws[OFF_XMEAN + tid] = meanX[tid];
        ws[OFF_XSTD  + tid] = stdX[tid];
    }
    if (tid < E) { ws[OFF_YMEAN + tid] = meanY[tid]; ws[OFF_YSTD + tid] = stdY[tid]; }
    __syncthreads();
    int n = tid;  // 512 rows
    #pragma unroll
    for (int d = 0; d < D; ++d) {
        float xs = (X[n*D + d] - meanX[d]) / stdX[d];
        ws[OFF_XS  + n*D + d] = xs;
        ws[OFF_INP + n*D + d] = xs - mmsh[d];
    }
    #pragma unroll
    for (int e = 0; e < E; ++e)
        ws[OFF_YN + e*N + n] = (Y[n*E + e] - meanY[e]) / stdY[e];
    if (tid < D*D) {
        int i = tid / D, j = tid % D;
        ws[OFF_SSM + tid] = s[tid] / (stdX[i] * stdX[j]);
    }
}

// ---------- 2. A = K + noise I (64x64 tiles) ----------
__global__ __launch_bounds__(256) void k_buildA(float* __restrict__ ws, const float* __restrict__ ls,
                                                const float* __restrict__ os, const float* __restrict__ noise) {
    int bid = blockIdx.x;            // E * 8 * 8
    int e  = bid >> 6;
    int t  = bid & 63;
    int bn = t >> 3, bm = t & 7;
    int tid = threadIdx.x;
    __shared__ float xn[64][17], xm[64][17];
    __shared__ float il2[16];
    for (int idx = tid; idx < 1024; idx += 256) {
        int r = idx >> 4, d0 = idx & 15;
        xn[r][d0] = ws[OFF_XS + (size_t)(bn*64 + r)*D + d0];
        xm[r][d0] = ws[OFF_XS + (size_t)(bm*64 + r)*D + d0];
    }
    if (tid < 16) { float l = ls[e*D + tid]; il2[tid] = 1.0f/(l*l); }
    __syncthreads();
    int tx = tid & 15, ty = tid >> 4;
    float osv = os[e], nsv = noise[e];
    float acc[4][4] = {};
    #pragma unroll
    for (int d = 0; d < 16; ++d) {
        float il = il2[d];
        float an[4], am[4];
        #pragma unroll
        for (int q = 0; q < 4; ++q) { an[q] = xn[ty + q*16][d]; am[q] = xm[tx + q*16][d]; }
        #pragma unroll
        for (int q = 0; q < 4; ++q)
            #pragma unroll
            for (int w = 0; w < 4; ++w) { float df = an[q] - am[w]; acc[q][w] = fmaf(df*df, il, acc[q][w]); }
    }
    float* A = ws + OFF_A + (size_t)e*N*N;
    #pragma unroll
    for (int q = 0; q < 4; ++q)
        #pragma unroll
        for (int w = 0; w < 4; ++w) {
            int nr = bn*64 + ty + q*16, mc = bm*64 + tx + w*16;
            float v = osv * __expf(-0.5f * acc[q][w]);
            if (nr == mc) v += nsv;
            A[(size_t)nr*N + mc] = v;
        }
}

// ---------- 3a. single-wave in-register 64x64 Cholesky + triangular inverse ----------
// lane r holds row r of the diag block in 64 VGPRs; all cross-lane via compile-time-lane shfl (readlane).
__global__ __launch_bounds__(64) void k_diag64(float* __restrict__ ws, int k0) {
    int e = blockIdx.x;
    int lane = threadIdx.x;
    const float* A = ws + OFF_A + (size_t)e*N*N;
    float* W = ws + OFF_IK + (size_t)e*N*N;
    float a[64];
    #pragma unroll
    for (int c = 0; c < 64; ++c) a[c] = A[(size_t)(k0 + lane)*N + k0 + c];
    // factor: right-looking, full-square update (upper half = dead values, never read)
    #pragma unroll
    for (int k = 0; k < 64; ++k) {
        float dk = __shfl(a[k], k);
        float dv = sqrtf(dk);
        float iv = 1.0f / dv;
        if (lane == k) a[k] = dv;
        else if (lane > k) a[k] *= iv;
        float lrk = a[k];
        #pragma unroll
        for (int c = k + 1; c < 64; ++c) {
            float lck = __shfl(a[k], c);       // L[c][k] (readlane)
            a[c] = fmaf(-lrk, lck, a[c]);
        }
    }
    // invert: lane c computes column c of W = L^{-1} (x[r]=0 for r<c falls out naturally)
    float x[64];
    int c = lane;
    #pragma unroll
    for (int r = 0; r < 64; ++r) {
        float acc = (r == c) ? 1.0f : 0.0f;
        #pragma unroll
        for (int k = 0; k < r; ++k) {
            float lrk = __shfl(a[k], r);       // L[r][k]
            acc = fmaf(-lrk, x[k], acc);
        }
        float lrr = __shfl(a[r], r);
        x[r] = acc / lrr;
    }
    #pragma unroll
    for (int r = 0; r < 64; ++r)
        W[(size_t)(k0 + r)*N + k0 + c] = x[r];
}

// ---------- 3b. panel TRSM as GEMM: P <- P * W_kk^T ----------
__global__ __launch_bounds__(256) void k_panelmul(float* __restrict__ ws, int k0) {
    int nb = (N - k0 - 64) >> 6;
    int e  = blockIdx.x / nb;
    int bi = blockIdx.x % nb;
    float* A = ws + OFF_A + (size_t)e*N*N;
    const float* W = ws + OFF_IK + (size_t)e*N*N;
    int r0 = k0 + 64 + bi*64;
    __shared__ float Ps[64][65], Wsh[64][65];
    int tid = threadIdx.x;
    for (int idx = tid; idx < 4096; idx += 256) {
        int r = idx >> 6, c2 = idx & 63;
        Ps[r][c2]  = A[(size_t)(r0 + r)*N + k0 + c2];
        Wsh[r][c2] = W[(size_t)(k0 + r)*N + k0 + c2];
    }
    __syncthreads();
    int tx = tid & 15, ty = tid >> 4;
    float acc[4][4] = {};
    #pragma unroll 8
    for (int j = 0; j < 64; ++j) {
        float pr[4], wr[4];
        #pragma unroll
        for (int q = 0; q < 4; ++q) { pr[q] = Ps[ty*4+q][j]; wr[q] = Wsh[tx*4+q][j]; }
        #pragma unroll
        for (int q = 0; q < 4; ++q)
            #pragma unroll
            for (int w = 0; w < 4; ++w) acc[q][w] = fmaf(pr[q], wr[w], acc[q][w]);
    }
    __syncthreads();
    #pragma unroll
    for (int q = 0; q < 4; ++q)
        #pragma unroll
        for (int w = 0; w < 4; ++w)
            A[(size_t)(r0 + ty*4 + q)*N + k0 + tx*4 + w] = acc[q][w];
}

// ---------- 3c. trailing SYRK update: A[tile] -= P_r P_c^T ----------
__global__ __launch_bounds__(256) void k_trail(float* __restrict__ ws, int k0) {
    int t0 = k0 + 64;
    int nb = (N - t0) >> 6;
    int ntiles = (nb*(nb+1)) >> 1;
    int e = blockIdx.x / ntiles;
    int t = blockIdx.x % ntiles;
    int bj = 0; while (t >= nb - bj) { t -= nb - bj; ++bj; }
    int bi = bj + t;
    float* A = ws + OFF_A + (size_t)e*N*N;
    const float* Pr = A + (size_t)(t0 + bi*64)*N + k0;
    const float* Pc = A + (size_t)(t0 + bj*64)*N + k0;
    __shared__ float Sr[64][65], Sc[64][65];
    int tid = threadIdx.x;
    for (int idx = tid; idx < 4096; idx += 256) {
        int r = idx >> 6, c = idx & 63;
        Sr[r][c] = Pr[(size_t)r*N + c];
        Sc[r][c] = Pc[(size_t)r*N + c];
    }
    __syncthreads();
    int tx = tid & 15, ty = tid >> 4;
    float acc[4][4] = {};
    #pragma unroll 8
    for (int p = 0; p < 64; ++p) {
        float ar[4], ac[4];
        #pragma unroll
        for (int q = 0; q < 4; ++q) { ar[q] = Sr[ty*4+q][p]; ac[q] = Sc[tx*4+q][p]; }
        #pragma unroll
        for (int q = 0; q < 4; ++q)
            #pragma unroll
            for (int w = 0; w < 4; ++w) acc[q][w] = fmaf(ar[q], ac[w], acc[q][w]);
    }
    float* Out = A + (size_t)(t0 + bi*64)*N + (t0 + bj*64);
    #pragma unroll
    for (int q = 0; q < 4; ++q)
        #pragma unroll
        for (int w = 0; w < 4; ++w)
            Out[(size_t)(ty*4+q)*N + tx*4+w] -= acc[q][w];
}

// ---------- 3d. triangular inverse off-diagonal wavefront d: W_ij = -W_ii (sum_k L_ik W_kj) ----------
__global__ __launch_bounds__(256) void k_tinv_off(float* __restrict__ ws, int d) {
    int e = blockIdx.x / (8 - d);
    int j = blockIdx.x % (8 - d);
    int i = j + d;
    const float* L = ws + OFF_A  + (size_t)e*N*N;
    float*       W = ws + OFF_IK + (size_t)e*N*N;
    __shared__ float Sa[64][65], Sb[64][65], T[64][65];
    int tid = threadIdx.x;
    int tx = tid & 15, ty = tid >> 4;
    float acc[4][4] = {};
    for (int k = j; k < i; ++k) {
        for (int idx = tid; idx < 4096; idx += 256) {
            int r = idx >> 6, cc = idx & 63;
            Sa[r][cc] = L[(size_t)(i*64+r)*N + k*64+cc];
            Sb[r][cc] = W[(size_t)(k*64+r)*N + j*64+cc];
        }
        __syncthreads();
        #pragma unroll 8
        for (int p = 0; p < 64; ++p) {
            float ar[4], ac[4];
            #pragma unroll
            for (int q = 0; q < 4; ++q) { ar[q] = Sa[ty*4+q][p]; ac[q] = Sb[p][tx*4+q]; }
            #pragma unroll
            for (int q = 0; q < 4; ++q)
                #pragma unroll
                for (int w = 0; w < 4; ++w) acc[q][w] = fmaf(ar[q], ac[w], acc[q][w]);
        }
        __syncthreads();
    }
    #pragma unroll
    for (int q = 0; q < 4; ++q)
        #pragma unroll
        for (int w = 0; w < 4; ++w) T[ty*4+q][tx*4+w] = acc[q][w];
    for (int idx = tid; idx < 4096; idx += 256) {
        int r = idx >> 6, cc = idx & 63;
        Sa[r][cc] = W[(size_t)(i*64+r)*N + i*64+cc];   // W_ii
    }
    __syncthreads();
    float o[4][4] = {};
    #pragma unroll 8
    for (int p = 0; p < 64; ++p) {
        float ar[4], ac[4];
        #pragma unroll
        for (int q = 0; q < 4; ++q) { ar[q] = Sa[ty*4+q][p]; ac[q] = T[p][tx*4+q]; }
        #pragma unroll
        for (int q = 0; q < 4; ++q)
            #pragma unroll
            for (int w = 0; w < 4; ++w) o[q][w] = fmaf(ar[q], ac[w], o[q][w]);
    }
    #pragma unroll
    for (int q = 0; q < 4; ++q)
        #pragma unroll
        for (int w = 0; w < 4; ++w)
            W[(size_t)(i*64+ty*4+q)*N + j*64+tx*4+w] = -o[q][w];
}

// ---------- 3e. iK = W^T W (into OFF_A, full symmetric) ----------
__global__ __launch_bounds__(256) void k_syrk(float* __restrict__ ws) {
    int e = blockIdx.x / 36;
    int t = blockIdx.x % 36;
    int bj = 0; while (t >= 8 - bj) { t -= 8 - bj; ++bj; }
    int bi = bj + t;                       // bi >= bj
    const float* W = ws + OFF_IK + (size_t)e*N*N;
    float*      IK = ws + OFF_A  + (size_t)e*N*N;
    __shared__ float Sa[64][65], Sb[64][65];
    int tid = threadIdx.x;
    int tx = tid & 15, ty = tid >> 4;
    float acc[4][4] = {};
    for (int p = bi; p < 8; ++p) {
        for (int idx = tid; idx < 4096; idx += 256) {
            int r = idx >> 6, cc = idx & 63;
            Sa[r][cc] = W[(size_t)(p*64+r)*N + bi*64+cc];
            Sb[r][cc] = W[(size_t)(p*64+r)*N + bj*64+cc];
        }
        __syncthreads();
        #pragma unroll 8
        for (int pr = 0; pr < 64; ++pr) {
            float ar[4], ac[4];
            #pragma unroll
            for (int q = 0; q < 4; ++q) { ar[q] = Sa[pr][ty*4+q]; ac[q] = Sb[pr][tx*4+q]; }
            #pragma unroll
            for (int q = 0; q < 4; ++q)
                #pragma unroll
                for (int w = 0; w < 4; ++w) acc[q][w] = fmaf(ar[q], ac[w], acc[q][w]);
        }
        __syncthreads();
    }
    #pragma unroll
    for (int q = 0; q < 4; ++q)
        #pragma unroll
        for (int w = 0; w < 4; ++w) {
            int r = bi*64 + ty*4 + q, c = bj*64 + tx*4 + w;
            IK[(size_t)r*N + c] = acc[q][w];
            IK[(size_t)c*N + r] = acc[q][w];
        }
}

// ---------- 3f. beta = iK @ Yn (column access, coalesced, iK symmetric) ----------
__global__ __launch_bounds__(256) void k_beta(float* __restrict__ ws) {
    int e = blockIdx.x >> 1;
    int half = blockIdx.x & 1;
    int n = half*256 + threadIdx.x;
    __shared__ float yn[N];
    for (int i = threadIdx.x; i < N; i += 256) yn[i] = ws[OFF_YN + (size_t)e*N + i];
    __syncthreads();
    const float* IK = ws + OFF_A + (size_t)e*N*N;
    float a0 = 0.f, a1 = 0.f, a2 = 0.f, a3 = 0.f;
    for (int mm = 0; mm < N; mm += 4) {
        a0 = fmaf(IK[(size_t)mm*N + n],     yn[mm],   a0);
        a1 = fmaf(IK[(size_t)(mm+1)*N + n], yn[mm+1], a1);
        a2 = fmaf(IK[(size_t)(mm+2)*N + n], yn[mm+2], a2);
        a3 = fmaf(IK[(size_t)(mm+3)*N + n], yn[mm+3], a3);
    }
    ws[OFF_BETA + e*N + n] = (a0 + a1) + (a2 + a3);
}

// ---------- 4a. B inverse + detB -> c ----------
__global__ __launch_bounds__(256) void k_B(float* __restrict__ ws, const float* __restrict__ ls,
                                           const float* __restrict__ os) {
    int e = blockIdx.x;
    int tid = threadIdx.x;
    int i = tid >> 4, j = tid & 15;
    __shared__ float Bm[16][17], Inv[16][17];
    float li = ls[e*D + i], lj = ls[e*D + j];
    Bm[i][j] = ws[OFF_SSM + i*D + j] / (li*lj) + ((i==j) ? 1.f : 0.f);
    Inv[i][j] = (i==j) ? 1.f : 0.f;
    __syncthreads();
    float det = 1.f;
    for (int k = 0; k < D; ++k) {
        float p   = Bm[k][k];
        float fik = Bm[i][k];
        float bkj = Bm[k][j];
        float ikj = Inv[k][j];
        __syncthreads();
        det *= p;
        if (i == k) { Bm[k][j] = bkj/p; Inv[k][j] = ikj/p; }
        else        { float f = fik/p; Bm[i][j] -= f*bkj; Inv[i][j] -= f*ikj; }
        __syncthreads();
    }
    ws[OFF_BINV + ((size_t)e*D + i)*D + j] = Inv[i][j];
    if (tid == 0) ws[OFF_C + e] = os[e] / sqrtf(det);
}

// ---------- 4b. R inverse, detR, Q = R^{-1} ss / 2 ----------
__global__ __launch_bounds__(256) void k_R(float* __restrict__ ws, const float* __restrict__ ls) {
    int pair = blockIdx.x;           // E*E
    int a = pair / E, b = pair % E;
    int tid = threadIdx.x;
    int i = tid >> 4, j = tid & 15;
    __shared__ float Rm[16][17], Inv[16][17], ssl[16][17];
    float la = ls[a*D + j], lb2 = ls[b*D + j];
    float rj = 1.f/(la*la) + 1.f/(lb2*lb2);
    float ssv = ws[OFF_SSM + i*D + j];
    ssl[i][j] = ssv;
    Rm[i][j] = ssv * rj + ((i==j) ? 1.f : 0.f);
    Inv[i][j] = (i==j) ? 1.f : 0.f;
    __syncthreads();
    float det = 1.f;
    for (int k = 0; k < D; ++k) {
        float p   = Rm[k][k];
        float fik = Rm[i][k];
        float rkj = Rm[k][j];
        float ikj = Inv[k][j];
        __syncthreads();
        det *= p;
        if (i == k) { Rm[k][j] = rkj/p; Inv[k][j] = ikj/p; }
        else        { float f = fik/p; Rm[i][j] -= f*rkj; Inv[i][j] -= f*ikj; }
        __syncthreads();
    }
    float q = 0.f;
    #pragma unroll
    for (int k2 = 0; k2 < D; ++k2) q += Inv[i][k2] * ssl[k2][j];
    ws[OFF_Q + ((size_t)pair*D + i)*D + j] = 0.5f * q;
    if (tid == 0) ws[OFF_ISDR + pair] = 1.f / sqrtf(det);
}

// ---------- 5. per (e,n): iN, t, lb, tiL, kvec, X1 ----------
__global__ __launch_bounds__(256) void k_point(float* __restrict__ ws, const float* __restrict__ ls,
                                               const float* __restrict__ os) {
    int t = blockIdx.x*256 + threadIdx.x;   // E*N
    int e = t >> 9, n = t & 511;
    float iN[D], tt[D], l[D];
    #pragma unroll
    for (int d = 0; d < D; ++d) { l[d] = ls[e*D + d]; iN[d] = ws[OFF_INP + n*D + d] / l[d]; }
    #pragma unroll
    for (int d = 0; d < D; ++d) {
        float acc = 0.f;
        #pragma unroll
        for (int j = 0; j < D; ++j) acc += ws[OFF_BINV + ((size_t)e*D + d)*D + j] * iN[j];
        tt[d] = acc;
    }
    float siNt = 0.f, siN2 = 0.f;
    #pragma unroll
    for (int d = 0; d < D; ++d) { siNt += iN[d]*tt[d]; siN2 += iN[d]*iN[d]; }
    float lbv = __expf(-0.5f * siNt) * ws[OFF_BETA + e*N + n];
    ws[OFF_LB + e*N + n] = lbv;
    #pragma unroll
    for (int d = 0; d < D; ++d) ws[OFF_TIL + ((size_t)e*N + n)*D + d] = tt[d] / l[d];
    ws[OFF_KVEC + e*N + n] = logf(os[e]) - 0.5f * siN2;
    #pragma unroll
    for (int d = 0; d < D; ++d) ws[OFF_X1 + ((size_t)e*N + n)*D + d] = ws[OFF_INP + n*D + d] / (l[d]*l[d]);
}

// ---------- 6. X1Q, Xs_, X2s per (a,b,n) ----------
__global__ __launch_bounds__(256) void k_x1q(float* __restrict__ ws) {
    int t = blockIdx.x*256 + threadIdx.x;   // E*E*N
    int pair = t / N, n = t % N;
    int a = pair / E, b = pair % E;
    __shared__ float Qs[16][16];
    Qs[threadIdx.x >> 4][threadIdx.x & 15] = ws[OFF_Q + (size_t)pair*D*D + threadIdx.x];
    __syncthreads();
    float x1a[D], x1b[D];
    #pragma unroll
    for (int d = 0; d < D; ++d) {
        x1a[d] = ws[OFF_X1 + ((size_t)a*N + n)*D + d];
        x1b[d] = ws[OFF_X1 + ((size_t)b*N + n)*D + d];
    }
    float xs1 = 0.f, xs2 = 0.f;
    #pragma unroll
    for (int j = 0; j < D; ++j) {
        float acc = 0.f, acc2 = 0.f;
        #pragma unroll
        for (int i = 0; i < D; ++i) { acc += x1a[i]*Qs[i][j]; acc2 += x1b[i]*Qs[i][j]; }
        ws[OFF_X1Q + ((size_t)pair*N + n)*D + j] = acc;
        xs1 += acc  * x1a[j];
        xs2 += acc2 * x1b[j];
    }
    ws[OFF_XS1 + (size_t)pair*N + n] = xs1;
    ws[OFF_XS2 + (size_t)pair*N + n] = xs2;
}

// ---------- 7. big cross-term: S partials + trace partials ----------
__global__ __launch_bounds__(256) void k_S(float* __restrict__ ws) {
    int bid = blockIdx.x;            // E*E*32
    int pair = bid >> 5, ntile = bid & 31;
    int a = pair / E, b = pair % E;
    int tid = threadIdx.x;
    int tn = tid >> 4, tm = tid & 15;
    __shared__ float x1q[16][17], x2t[16][17];
    __shared__ float ka[16], bea[16], xs1[16], kb[16], beb[16], xs2[16];
    __shared__ float red[256];
    int n = ntile*16 + tn;
    {
        int r = tid >> 4, d0 = tid & 15;
        x1q[r][d0] = ws[OFF_X1Q + ((size_t)pair*N + ntile*16 + r)*D + d0];
        if (tid < 16) {
            int nn = ntile*16 + tid;
            ka[tid]  = ws[OFF_KVEC + a*N + nn];
            bea[tid] = ws[OFF_BETA + a*N + nn];
            xs1[tid] = ws[OFF_XS1 + (size_t)pair*N + nn];
        }
    }
    float acc = 0.f, accT = 0.f;
    const float* IKrow = ws + OFF_A + ((size_t)a*N + n)*N;
    for (int mt = 0; mt < 32; ++mt) {
        __syncthreads();
        int r = tid >> 4, d0 = tid & 15;
        x2t[r][d0] = ws[OFF_X1 + ((size_t)b*N + mt*16 + r)*D + d0];
        if (tid < 16) {
            int mmm = mt*16 + tid;
            kb[tid]  = ws[OFF_KVEC + b*N + mmm];
            beb[tid] = ws[OFF_BETA + b*N + mmm];
            xs2[tid] = ws[OFF_XS2 + (size_t)pair*N + mmm];
        }
        __syncthreads();
        float dot = 0.f;
        #pragma unroll
        for (int d = 0; d < D; ++d) dot += x1q[tn][d] * x2t[tm][d];
        float maha = 2.f*dot + xs1[tn] + xs2[tm];
        float Lv = __expf(ka[tn] + kb[tm] + maha);
        acc += bea[tn] * Lv * beb[tm];
        if (a == b) accT += IKrow[mt*16 + tm] * Lv;
    }
    red[tid] = acc; __syncthreads();
    for (int o = 128; o > 0; o >>= 1) { if (tid < o) red[tid] += red[tid+o]; __syncthreads(); }
    if (tid == 0) ws[OFF_SPART + bid] = red[0];
    if (a == b) {
        __syncthreads();
        red[tid] = accT; __syncthreads();
        for (int o = 128; o > 0; o >>= 1) { if (tid < o) red[tid] += red[tid+o]; __syncthreads(); }
        if (tid == 0) ws[OFF_TPART + a*32 + ntile] = red[0];
    }
}

// ---------- 8. finalize ----------
__global__ __launch_bounds__(256) void k_final(float* __restrict__ ws, const float* __restrict__ s,
                                               const float* __restrict__ os, float* __restrict__ out) {
    int tid = threadIdx.x;  // 256
    __shared__ float red[256];
    __shared__ float Msh[E], Vsh[E][D], cov[D][E+1];
    __shared__ float Sm[16][17], Si[16][17];

    for (int e = 0; e < E; ++e) {
        float p = 0.f;
        for (int n = tid; n < N; n += 256) p += ws[OFF_LB + e*N + n];
        red[tid] = p; __syncthreads();
        for (int o = 128; o > 0; o >>= 1) { if (tid < o) red[tid] += red[tid+o]; __syncthreads(); }
        if (tid == 0) Msh[e] = ws[OFF_C + e] * red[0];
        __syncthreads();
    }
    if (tid < E*D) {
        int e = tid / D, d = tid % D;
        float acc = 0.f;
        for (int n = 0; n < N; ++n)
            acc += ws[OFF_TIL + ((size_t)e*N + n)*D + d] * ws[OFF_LB + e*N + n];
        Vsh[e][d] = ws[OFF_C + e] * acc;
    }
    __syncthreads();

    if (tid < E*E) {
        int a = tid / E, bb = tid % E;
        float acc = 0.f;
        for (int q = 0; q < 32; ++q) acc += ws[OFF_SPART + (size_t)tid*32 + q];
        if (a == bb) {
            float tr = 0.f;
            for (int q = 0; q < 32; ++q) tr += ws[OFF_TPART + a*32 + q];
            acc -= tr;
        }
        acc *= ws[OFF_ISDR + tid];
        if (a == bb) acc += os[a];
        float v = acc - Msh[a]*Msh[bb];
        v *= ws[OFF_YSTD + a] * ws[OFF_YSTD + bb];
        out[E + tid] = v;                                // S
    }
    if (tid < E) out[tid] = Msh[tid]*ws[OFF_YSTD + tid] + ws[OFF_YMEAN + tid];  // Mout

    if (tid < D*E) {
        int d = tid / E, e = tid % E;
        float acc = 0.f;
        for (int k = 0; k < D; ++k) acc += ws[OFF_SSM + d*D + k] * Vsh[e][k];
        cov[d][e] = acc * ws[OFF_XSTD + d] * ws[OFF_YSTD + e];
    }
    int i = tid >> 4, j = tid & 15;
    Sm[i][j] = s[i*D + j];
    Si[i][j] = (i==j) ? 1.f : 0.f;
    __syncthreads();
    for (int k = 0; k < D; ++k) {
        float p   = Sm[k][k];
        float fik = Sm[i][k];
        float skj = Sm[k][j];
        float ikj = Si[k][j];
        __syncthreads();
        if (i == k) { Sm[k][j] = skj/p; Si[k][j] = ikj/p; }
        else        { float f = fik/p; Sm[i][j] -= f*skj; Si[i][j] -= f*ikj; }
        __syncthreads();
    }
    if (tid < D*E) {
        int d = tid / E, e = tid % E;
        float acc = 0.f;
        for (int k = 0; k < D; ++k) acc += Si[d][k] * cov[k][e];
        out[E + E*E + d*E + e] = acc;                    // Vout
    }
}

extern "C" void kernel_launch(void* const* d_in, const int* in_sizes, int n_in,
                              void* d_out, int out_size, void* d_ws, size_t ws_size,
                              hipStream_t stream) {
    const float* X     = (const float*)d_in[0];
    const float* Y     = (const float*)d_in[1];
    const float* m     = (const float*)d_in[2];
    const float* s     = (const float*)d_in[3];
    const float* ls    = (const float*)d_in[4];
    const float* os    = (const float*)d_in[5];
    const float* noise = (const float*)d_in[6];
    float* ws  = (float*)d_ws;
    float* out = (float*)d_out;

    k_prep  <<<1,    512, 0, stream>>>(X, Y, m, s, ws);
    k_buildA<<<E*64, 256, 0, stream>>>(ws, ls, os, noise);
    for (int kk = 0; kk < 8; ++kk) {
        int k0 = kk*64;
        k_diag64<<<E, 64, 0, stream>>>(ws, k0);
        int nb = 7 - kk;
        if (nb > 0) {
            k_panelmul<<<E*nb, 256, 0, stream>>>(ws, k0);
            k_trail<<<E*nb*(nb+1)/2, 256, 0, stream>>>(ws, k0);
        }
    }
    for (int d = 1; d < 8; ++d)
        k_tinv_off<<<E*(8-d), 256, 0, stream>>>(ws, d);
    k_syrk <<<E*36,      256, 0, stream>>>(ws);
    k_beta <<<E*2,       256, 0, stream>>>(ws);
    k_B    <<<E,         256, 0, stream>>>(ws, ls, os);
    k_R    <<<E*E,       256, 0, stream>>>(ws, ls);
    k_point<<<E*N/256,   256, 0, stream>>>(ws, ls, os);
    k_x1q  <<<E*E*N/256, 256, 0, stream>>>(ws);
    k_S    <<<E*E*32,    256, 0, stream>>>(ws);
    k_final<<<1,         256, 0, stream>>>(ws, s, os, out);
}

// Round 4
// 1106.029 us; speedup vs baseline: 1.5637x; 1.5637x over previous
//
#include <hip/hip_runtime.h>
#include <math.h>

constexpr int N = 512;
constexpr int D = 16;
constexpr int E = 12;

// ---- workspace layout (float offsets) ----
// OFF_A:  A -> L panels (Cholesky) -> iK (after SYRK)
// OFF_IK: W = L^{-1}
constexpr size_t OFF_A     = 0;                            // E*N*N
constexpr size_t OFF_IK    = OFF_A    + (size_t)E*N*N;     // E*N*N
constexpr size_t OFF_XS    = OFF_IK   + (size_t)E*N*N;     // N*D
constexpr size_t OFF_INP   = OFF_XS   + (size_t)N*D;       // N*D
constexpr size_t OFF_YN    = OFF_INP  + (size_t)N*D;       // E*N
constexpr size_t OFF_BETA  = OFF_YN   + (size_t)E*N;       // E*N
constexpr size_t OFF_KVEC  = OFF_BETA + (size_t)E*N;       // E*N
constexpr size_t OFF_LB    = OFF_KVEC + (size_t)E*N;       // E*N
constexpr size_t OFF_TIL   = OFF_LB   + (size_t)E*N;       // E*N*D
constexpr size_t OFF_X1    = OFF_TIL  + (size_t)E*N*D;     // E*N*D
constexpr size_t OFF_X1Q   = OFF_X1   + (size_t)E*N*D;     // E*E*N*D
constexpr size_t OFF_XS1   = OFF_X1Q  + (size_t)E*E*N*D;   // E*E*N
constexpr size_t OFF_XS2   = OFF_XS1  + (size_t)E*E*N;     // E*E*N
constexpr size_t OFF_Q     = OFF_XS2  + (size_t)E*E*N;     // E*E*D*D
constexpr size_t OFF_BINV  = OFF_Q    + (size_t)E*E*D*D;   // E*D*D
constexpr size_t OFF_C     = OFF_BINV + (size_t)E*D*D;     // E
constexpr size_t OFF_ISDR  = OFF_C    + E;                 // E*E
constexpr size_t OFF_SPART = OFF_ISDR + E*E;               // E*E*32
constexpr size_t OFF_TPART = OFF_SPART+ (size_t)E*E*32;    // E*32
constexpr size_t OFF_XMEAN = OFF_TPART+ (size_t)E*32;      // D
constexpr size_t OFF_XSTD  = OFF_XMEAN+ D;                 // D
constexpr size_t OFF_YMEAN = OFF_XSTD + D;                 // E
constexpr size_t OFF_YSTD  = OFF_YMEAN+ E;                 // E
constexpr size_t OFF_SSM   = OFF_YSTD + E;                 // D*D

// ---------- 1. standardization (wave-shuffle reductions, few barriers) ----------
__global__ __launch_bounds__(512) void k_prep(const float* __restrict__ X, const float* __restrict__ Y,
                                              const float* __restrict__ m, const float* __restrict__ s,
                                              float* __restrict__ ws) {
    int tid = threadIdx.x;
    int lane = tid & 63, wave = tid >> 6;   // 8 waves
    __shared__ float meanX[D], stdX[D], meanY[E], stdY[E], mmsh[D];

    for (int col = wave; col < D + E; col += 8) {
        float s1 = 0.f, s2 = 0.f;
        if (col < D) {
            #pragma unroll
            for (int i = 0; i < 8; ++i) { float v = X[(i*64 + lane)*D + col]; s1 += v; s2 += v*v; }
        } else {
            int e = col - D;
            #pragma unroll
            for (int i = 0; i < 8; ++i) { float v = Y[(i*64 + lane)*E + e]; s1 += v; s2 += v*v; }
        }
        #pragma unroll
        for (int off = 32; off > 0; off >>= 1) { s1 += __shfl_xor(s1, off); s2 += __shfl_xor(s2, off); }
        if (lane == 0) {
            float mean = s1 * (1.0f/N);
            float var  = (s2 - (float)N*mean*mean) * (1.0f/(N-1));
            float sd   = sqrtf(var);
            if (col < D) { meanX[col] = mean; stdX[col] = sd; }
            else         { meanY[col-D] = mean; stdY[col-D] = sd; }
        }
    }
    __syncthreads();
    if (tid < D) {
        mmsh[tid] = (m[tid] - meanX[tid]) / stdX[tid];
        ws[OFF_XMEAN + tid] = meanX[tid];
        ws[OFF_XSTD  + tid] = stdX[tid];
    }
    if (tid < E) { ws[OFF_YMEAN + tid] = meanY[tid]; ws[OFF_YSTD + tid] = stdY[tid]; }
    __syncthreads();
    int n = tid;  // 512 rows
    #pragma unroll
    for (int d = 0; d < D; ++d) {
        float xs = (X[n*D + d] - meanX[d]) / stdX[d];
        ws[OFF_XS  + n*D + d] = xs;
        ws[OFF_INP + n*D + d] = xs - mmsh[d];
    }
    #pragma unroll
    for (int e = 0; e < E; ++e)
        ws[OFF_YN + e*N + n] = (Y[n*E + e] - meanY[e]) / stdY[e];
    if (tid < D*D) {
        int i = tid / D, j = tid % D;
        ws[OFF_SSM + tid] = s[tid] / (stdX[i] * stdX[j]);
    }
}

// ---------- 2. A = K + noise I (64x64 tiles) ----------
__global__ __launch_bounds__(256) void k_buildA(float* __restrict__ ws, const float* __restrict__ ls,
                                                const float* __restrict__ os, const float* __restrict__ noise) {
    int bid = blockIdx.x;            // E * 8 * 8
    int e  = bid >> 6;
    int t  = bid & 63;
    int bn = t >> 3, bm = t & 7;
    int tid = threadIdx.x;
    __shared__ float xn[64][17], xm[64][17];
    __shared__ float il2[16];
    for (int idx = tid; idx < 1024; idx += 256) {
        int r = idx >> 4, d0 = idx & 15;
        xn[r][d0] = ws[OFF_XS + (size_t)(bn*64 + r)*D + d0];
        xm[r][d0] = ws[OFF_XS + (size_t)(bm*64 + r)*D + d0];
    }
    if (tid < 16) { float l = ls[e*D + tid]; il2[tid] = 1.0f/(l*l); }
    __syncthreads();
    int tx = tid & 15, ty = tid >> 4;
    float osv = os[e], nsv = noise[e];
    float acc[4][4] = {};
    #pragma unroll
    for (int d = 0; d < 16; ++d) {
        float il = il2[d];
        float an[4], am[4];
        #pragma unroll
        for (int q = 0; q < 4; ++q) { an[q] = xn[ty + q*16][d]; am[q] = xm[tx + q*16][d]; }
        #pragma unroll
        for (int q = 0; q < 4; ++q)
            #pragma unroll
            for (int w = 0; w < 4; ++w) { float df = an[q] - am[w]; acc[q][w] = fmaf(df*df, il, acc[q][w]); }
    }
    float* A = ws + OFF_A + (size_t)e*N*N;
    #pragma unroll
    for (int q = 0; q < 4; ++q)
        #pragma unroll
        for (int w = 0; w < 4; ++w) {
            int nr = bn*64 + ty + q*16, mc = bm*64 + tx + w*16;
            float v = osv * __expf(-0.5f * acc[q][w]);
            if (nr == mc) v += nsv;
            A[(size_t)nr*N + mc] = v;
        }
}

// ---------- 3a. single-wave 64x64 Cholesky + triangular inverse (LDS broadcast, no spill) ----------
// Phase 1: lane r owns row r in a[64] (only big array live). Column broadcasts via colbuf LDS.
// Phase 2: a[] stored to Lsh then dead; lane c computes column c of W = L^{-1} in x[64].
__global__ __launch_bounds__(64) void k_diag64(float* __restrict__ ws, int k0) {
    int e = blockIdx.x;
    int lane = threadIdx.x;
    const float* A = ws + OFF_A + (size_t)e*N*N;
    float* W = ws + OFF_IK + (size_t)e*N*N;
    __shared__ float Lsh[64][68];     // row stride 272B (16B aligned)
    __shared__ float colbuf[64];
    __shared__ float invdsh[64];

    // load (A symmetric -> column read is coalesced across lanes)
    float a[64];
    #pragma unroll
    for (int c = 0; c < 64; ++c) a[c] = A[(size_t)(k0 + c)*N + k0 + lane];

    // factor: right-looking; rows < k hold dead values, never consumed
    #pragma unroll
    for (int k = 0; k < 64; ++k) {
        colbuf[lane] = a[k];
        __syncthreads();
        float dkk = colbuf[k];
        float dv = sqrtf(dkk), iv = 1.0f/dv;
        if (lane == k) { a[k] = dv; invdsh[k] = iv; }
        else if (lane > k) a[k] *= iv;
        colbuf[lane] = a[k];
        __syncthreads();
        float lrk = a[k];
        #pragma unroll
        for (int c = k + 1; c < 64; ++c)
            a[c] = fmaf(-lrk, colbuf[c], a[c]);
        __syncthreads();
    }

    // store L to LDS (a[] dead afterwards)
    #pragma unroll
    for (int c4 = 0; c4 < 16; ++c4) {
        float4 v; v.x = a[c4*4]; v.y = a[c4*4+1]; v.z = a[c4*4+2]; v.w = a[c4*4+3];
        *(float4*)&Lsh[lane][c4*4] = v;
    }
    __syncthreads();

    // invert: lane c computes column c of W (x[r]=0 for r<c falls out naturally)
    float x[64];
    int c = lane;
    #pragma unroll
    for (int r = 0; r < 64; ++r) {
        float acc0 = (r == c) ? 1.0f : 0.0f, acc1 = 0.f, acc2 = 0.f, acc3 = 0.f;
        #pragma unroll
        for (int k4 = 0; k4 < (r >> 2); ++k4) {
            float4 L4 = *(const float4*)&Lsh[r][k4*4];
            acc0 = fmaf(-L4.x, x[k4*4+0], acc0);
            acc1 = fmaf(-L4.y, x[k4*4+1], acc1);
            acc2 = fmaf(-L4.z, x[k4*4+2], acc2);
            acc3 = fmaf(-L4.w, x[k4*4+3], acc3);
        }
        #pragma unroll
        for (int k = r & ~3; k < r; ++k)
            acc0 = fmaf(-Lsh[r][k], x[k], acc0);
        x[r] = ((acc0 + acc1) + (acc2 + acc3)) * invdsh[r];
    }
    #pragma unroll
    for (int r = 0; r < 64; ++r)
        W[(size_t)(k0 + r)*N + k0 + c] = x[r];   // coalesced across lanes
}

// ---------- 3b. panel TRSM as GEMM: P <- P * W_kk^T ----------
__global__ __launch_bounds__(256) void k_panelmul(float* __restrict__ ws, int k0) {
    int nb = (N - k0 - 64) >> 6;
    int e  = blockIdx.x / nb;
    int bi = blockIdx.x % nb;
    float* A = ws + OFF_A + (size_t)e*N*N;
    const float* W = ws + OFF_IK + (size_t)e*N*N;
    int r0 = k0 + 64 + bi*64;
    __shared__ float Ps[64][65], Wsh[64][65];
    int tid = threadIdx.x;
    for (int idx = tid; idx < 4096; idx += 256) {
        int r = idx >> 6, c2 = idx & 63;
        Ps[r][c2]  = A[(size_t)(r0 + r)*N + k0 + c2];
        Wsh[r][c2] = W[(size_t)(k0 + r)*N + k0 + c2];
    }
    __syncthreads();
    int tx = tid & 15, ty = tid >> 4;
    float acc[4][4] = {};
    #pragma unroll 8
    for (int j = 0; j < 64; ++j) {
        float pr[4], wr[4];
        #pragma unroll
        for (int q = 0; q < 4; ++q) { pr[q] = Ps[ty*4+q][j]; wr[q] = Wsh[tx*4+q][j]; }
        #pragma unroll
        for (int q = 0; q < 4; ++q)
            #pragma unroll
            for (int w = 0; w < 4; ++w) acc[q][w] = fmaf(pr[q], wr[w], acc[q][w]);
    }
    __syncthreads();
    #pragma unroll
    for (int q = 0; q < 4; ++q)
        #pragma unroll
        for (int w = 0; w < 4; ++w)
            A[(size_t)(r0 + ty*4 + q)*N + k0 + tx*4 + w] = acc[q][w];
}

// ---------- 3c. trailing SYRK update: A[tile] -= P_r P_c^T ----------
__global__ __launch_bounds__(256) void k_trail(float* __restrict__ ws, int k0) {
    int t0 = k0 + 64;
    int nb = (N - t0) >> 6;
    int ntiles = (nb*(nb+1)) >> 1;
    int e = blockIdx.x / ntiles;
    int t = blockIdx.x % ntiles;
    int bj = 0; while (t >= nb - bj) { t -= nb - bj; ++bj; }
    int bi = bj + t;
    float* A = ws + OFF_A + (size_t)e*N*N;
    const float* Pr = A + (size_t)(t0 + bi*64)*N + k0;
    const float* Pc = A + (size_t)(t0 + bj*64)*N + k0;
    __shared__ float Sr[64][65], Sc[64][65];
    int tid = threadIdx.x;
    for (int idx = tid; idx < 4096; idx += 256) {
        int r = idx >> 6, c = idx & 63;
        Sr[r][c] = Pr[(size_t)r*N + c];
        Sc[r][c] = Pc[(size_t)r*N + c];
    }
    __syncthreads();
    int tx = tid & 15, ty = tid >> 4;
    float acc[4][4] = {};
    #pragma unroll 8
    for (int p = 0; p < 64; ++p) {
        float ar[4], ac[4];
        #pragma unroll
        for (int q = 0; q < 4; ++q) { ar[q] = Sr[ty*4+q][p]; ac[q] = Sc[tx*4+q][p]; }
        #pragma unroll
        for (int q = 0; q < 4; ++q)
            #pragma unroll
            for (int w = 0; w < 4; ++w) acc[q][w] = fmaf(ar[q], ac[w], acc[q][w]);
    }
    float* Out = A + (size_t)(t0 + bi*64)*N + (t0 + bj*64);
    #pragma unroll
    for (int q = 0; q < 4; ++q)
        #pragma unroll
        for (int w = 0; w < 4; ++w)
            Out[(size_t)(ty*4+q)*N + tx*4+w] -= acc[q][w];
}

// ---------- 3d. triangular inverse off-diagonal wavefront d: W_ij = -W_ii (sum_k L_ik W_kj) ----------
__global__ __launch_bounds__(256) void k_tinv_off(float* __restrict__ ws, int d) {
    int e = blockIdx.x / (8 - d);
    int j = blockIdx.x % (8 - d);
    int i = j + d;
    const float* L = ws + OFF_A  + (size_t)e*N*N;
    float*       W = ws + OFF_IK + (size_t)e*N*N;
    __shared__ float Sa[64][65], Sb[64][65], T[64][65];
    int tid = threadIdx.x;
    int tx = tid & 15, ty = tid >> 4;
    float acc[4][4] = {};
    for (int k = j; k < i; ++k) {
        for (int idx = tid; idx < 4096; idx += 256) {
            int r = idx >> 6, cc = idx & 63;
            Sa[r][cc] = L[(size_t)(i*64+r)*N + k*64+cc];
            Sb[r][cc] = W[(size_t)(k*64+r)*N + j*64+cc];
        }
        __syncthreads();
        #pragma unroll 8
        for (int p = 0; p < 64; ++p) {
            float ar[4], ac[4];
            #pragma unroll
            for (int q = 0; q < 4; ++q) { ar[q] = Sa[ty*4+q][p]; ac[q] = Sb[p][tx*4+q]; }
            #pragma unroll
            for (int q = 0; q < 4; ++q)
                #pragma unroll
                for (int w = 0; w < 4; ++w) acc[q][w] = fmaf(ar[q], ac[w], acc[q][w]);
        }
        __syncthreads();
    }
    #pragma unroll
    for (int q = 0; q < 4; ++q)
        #pragma unroll
        for (int w = 0; w < 4; ++w) T[ty*4+q][tx*4+w] = acc[q][w];
    for (int idx = tid; idx < 4096; idx += 256) {
        int r = idx >> 6, cc = idx & 63;
        Sa[r][cc] = W[(size_t)(i*64+r)*N + i*64+cc];   // W_ii
    }
    __syncthreads();
    float o[4][4] = {};
    #pragma unroll 8
    for (int p = 0; p < 64; ++p) {
        float ar[4], ac[4];
        #pragma unroll
        for (int q = 0; q < 4; ++q) { ar[q] = Sa[ty*4+q][p]; ac[q] = T[p][tx*4+q]; }
        #pragma unroll
        for (int q = 0; q < 4; ++q)
            #pragma unroll
            for (int w = 0; w < 4; ++w) o[q][w] = fmaf(ar[q], ac[w], o[q][w]);
    }
    #pragma unroll
    for (int q = 0; q < 4; ++q)
        #pragma unroll
        for (int w = 0; w < 4; ++w)
            W[(size_t)(i*64+ty*4+q)*N + j*64+tx*4+w] = -o[q][w];
}

// ---------- 3e. iK = W^T W (into OFF_A, full symmetric) ----------
__global__ __launch_bounds__(256) void k_syrk(float* __restrict__ ws) {
    int e = blockIdx.x / 36;
    int t = blockIdx.x % 36;
    int bj = 0; while (t >= 8 - bj) { t -= 8 - bj; ++bj; }
    int bi = bj + t;                       // bi >= bj
    const float* W = ws + OFF_IK + (size_t)e*N*N;
    float*      IK = ws + OFF_A  + (size_t)e*N*N;
    __shared__ float Sa[64][65], Sb[64][65];
    int tid = threadIdx.x;
    int tx = tid & 15, ty = tid >> 4;
    float acc[4][4] = {};
    for (int p = bi; p < 8; ++p) {
        for (int idx = tid; idx < 4096; idx += 256) {
            int r = idx >> 6, cc = idx & 63;
            Sa[r][cc] = W[(size_t)(p*64+r)*N + bi*64+cc];
            Sb[r][cc] = W[(size_t)(p*64+r)*N + bj*64+cc];
        }
        __syncthreads();
        #pragma unroll 8
        for (int pr = 0; pr < 64; ++pr) {
            float ar[4], ac[4];
            #pragma unroll
            for (int q = 0; q < 4; ++q) { ar[q] = Sa[pr][ty*4+q]; ac[q] = Sb[pr][tx*4+q]; }
            #pragma unroll
            for (int q = 0; q < 4; ++q)
                #pragma unroll
                for (int w = 0; w < 4; ++w) acc[q][w] = fmaf(ar[q], ac[w], acc[q][w]);
        }
        __syncthreads();
    }
    #pragma unroll
    for (int q = 0; q < 4; ++q)
        #pragma unroll
        for (int w = 0; w < 4; ++w) {
            int r = bi*64 + ty*4 + q, c = bj*64 + tx*4 + w;
            IK[(size_t)r*N + c] = acc[q][w];
            IK[(size_t)c*N + r] = acc[q][w];
        }
}

// ---------- 3f. beta = iK @ Yn (column access, coalesced, iK symmetric) ----------
__global__ __launch_bounds__(256) void k_beta(float* __restrict__ ws) {
    int e = blockIdx.x >> 1;
    int half = blockIdx.x & 1;
    int n = half*256 + threadIdx.x;
    __shared__ float yn[N];
    for (int i = threadIdx.x; i < N; i += 256) yn[i] = ws[OFF_YN + (size_t)e*N + i];
    __syncthreads();
    const float* IK = ws + OFF_A + (size_t)e*N*N;
    float a0 = 0.f, a1 = 0.f, a2 = 0.f, a3 = 0.f;
    for (int mm = 0; mm < N; mm += 4) {
        a0 = fmaf(IK[(size_t)mm*N + n],     yn[mm],   a0);
        a1 = fmaf(IK[(size_t)(mm+1)*N + n], yn[mm+1], a1);
        a2 = fmaf(IK[(size_t)(mm+2)*N + n], yn[mm+2], a2);
        a3 = fmaf(IK[(size_t)(mm+3)*N + n], yn[mm+3], a3);
    }
    ws[OFF_BETA + e*N + n] = (a0 + a1) + (a2 + a3);
}

// ---------- 4a. B inverse + detB -> c ----------
__global__ __launch_bounds__(256) void k_B(float* __restrict__ ws, const float* __restrict__ ls,
                                           const float* __restrict__ os) {
    int e = blockIdx.x;
    int tid = threadIdx.x;
    int i = tid >> 4, j = tid & 15;
    __shared__ float Bm[16][17], Inv[16][17];
    float li = ls[e*D + i], lj = ls[e*D + j];
    Bm[i][j] = ws[OFF_SSM + i*D + j] / (li*lj) + ((i==j) ? 1.f : 0.f);
    Inv[i][j] = (i==j) ? 1.f : 0.f;
    __syncthreads();
    float det = 1.f;
    for (int k = 0; k < D; ++k) {
        float p   = Bm[k][k];
        float fik = Bm[i][k];
        float bkj = Bm[k][j];
        float ikj = Inv[k][j];
        __syncthreads();
        det *= p;
        if (i == k) { Bm[k][j] = bkj/p; Inv[k][j] = ikj/p; }
        else        { float f = fik/p; Bm[i][j] -= f*bkj; Inv[i][j] -= f*ikj; }
        __syncthreads();
    }
    ws[OFF_BINV + ((size_t)e*D + i)*D + j] = Inv[i][j];
    if (tid == 0) ws[OFF_C + e] = os[e] / sqrtf(det);
}

// ---------- 4b. R inverse, detR, Q = R^{-1} ss / 2 ----------
__global__ __launch_bounds__(256) void k_R(float* __restrict__ ws, const float* __restrict__ ls) {
    int pair = blockIdx.x;           // E*E
    int a = pair / E, b = pair % E;
    int tid = threadIdx.x;
    int i = tid >> 4, j = tid & 15;
    __shared__ float Rm[16][17], Inv[16][17], ssl[16][17];
    float la = ls[a*D + j], lb2 = ls[b*D + j];
    float rj = 1.f/(la*la) + 1.f/(lb2*lb2);
    float ssv = ws[OFF_SSM + i*D + j];
    ssl[i][j] = ssv;
    Rm[i][j] = ssv * rj + ((i==j) ? 1.f : 0.f);
    Inv[i][j] = (i==j) ? 1.f : 0.f;
    __syncthreads();
    float det = 1.f;
    for (int k = 0; k < D; ++k) {
        float p   = Rm[k][k];
        float fik = Rm[i][k];
        float rkj = Rm[k][j];
        float ikj = Inv[k][j];
        __syncthreads();
        det *= p;
        if (i == k) { Rm[k][j] = rkj/p; Inv[k][j] = ikj/p; }
        else        { float f = fik/p; Rm[i][j] -= f*rkj; Inv[i][j] -= f*ikj; }
        __syncthreads();
    }
    float q = 0.f;
    #pragma unroll
    for (int k2 = 0; k2 < D; ++k2) q += Inv[i][k2] * ssl[k2][j];
    ws[OFF_Q + ((size_t)pair*D + i)*D + j] = 0.5f * q;
    if (tid == 0) ws[OFF_ISDR + pair] = 1.f / sqrtf(det);
}

// ---------- 5. per (e,n): iN, t, lb, tiL, kvec, X1 ----------
__global__ __launch_bounds__(256) void k_point(float* __restrict__ ws, const float* __restrict__ ls,
                                               const float* __restrict__ os) {
    int t = blockIdx.x*256 + threadIdx.x;   // E*N
    int e = t >> 9, n = t & 511;
    float iN[D], tt[D], l[D];
    #pragma unroll
    for (int d = 0; d < D; ++d) { l[d] = ls[e*D + d]; iN[d] = ws[OFF_INP + n*D + d] / l[d]; }
    #pragma unroll
    for (int d = 0; d < D; ++d) {
        float acc = 0.f;
        #pragma unroll
        for (int j = 0; j < D; ++j) acc += ws[OFF_BINV + ((size_t)e*D + d)*D + j] * iN[j];
        tt[d] = acc;
    }
    float siNt = 0.f, siN2 = 0.f;
    #pragma unroll
    for (int d = 0; d < D; ++d) { siNt += iN[d]*tt[d]; siN2 += iN[d]*iN[d]; }
    float lbv = __expf(-0.5f * siNt) * ws[OFF_BETA + e*N + n];
    ws[OFF_LB + e*N + n] = lbv;
    #pragma unroll
    for (int d = 0; d < D; ++d) ws[OFF_TIL + ((size_t)e*N + n)*D + d] = tt[d] / l[d];
    ws[OFF_KVEC + e*N + n] = logf(os[e]) - 0.5f * siN2;
    #pragma unroll
    for (int d = 0; d < D; ++d) ws[OFF_X1 + ((size_t)e*N + n)*D + d] = ws[OFF_INP + n*D + d] / (l[d]*l[d]);
}

// ---------- 6. X1Q, Xs_, X2s per (a,b,n) ----------
__global__ __launch_bounds__(256) void k_x1q(float* __restrict__ ws) {
    int t = blockIdx.x*256 + threadIdx.x;   // E*E*N
    int pair = t / N, n = t % N;
    int a = pair / E, b = pair % E;
    __shared__ float Qs[16][16];
    Qs[threadIdx.x >> 4][threadIdx.x & 15] = ws[OFF_Q + (size_t)pair*D*D + threadIdx.x];
    __syncthreads();
    float x1a[D], x1b[D];
    #pragma unroll
    for (int d = 0; d < D; ++d) {
        x1a[d] = ws[OFF_X1 + ((size_t)a*N + n)*D + d];
        x1b[d] = ws[OFF_X1 + ((size_t)b*N + n)*D + d];
    }
    float xs1 = 0.f, xs2 = 0.f;
    #pragma unroll
    for (int j = 0; j < D; ++j) {
        float acc = 0.f, acc2 = 0.f;
        #pragma unroll
        for (int i = 0; i < D; ++i) { acc += x1a[i]*Qs[i][j]; acc2 += x1b[i]*Qs[i][j]; }
        ws[OFF_X1Q + ((size_t)pair*N + n)*D + j] = acc;
        xs1 += acc  * x1a[j];
        xs2 += acc2 * x1b[j];
    }
    ws[OFF_XS1 + (size_t)pair*N + n] = xs1;
    ws[OFF_XS2 + (size_t)pair*N + n] = xs2;
}

// ---------- 7. big cross-term: S partials + trace partials ----------
__global__ __launch_bounds__(256) void k_S(float* __restrict__ ws) {
    int bid = blockIdx.x;            // E*E*32
    int pair = bid >> 5, ntile = bid & 31;
    int a = pair / E, b = pair % E;
    int tid = threadIdx.x;
    int tn = tid >> 4, tm = tid & 15;
    __shared__ float x1q[16][17], x2t[16][17];
    __shared__ float ka[16], bea[16], xs1[16], kb[16], beb[16], xs2[16];
    __shared__ float red[256];
    int n = ntile*16 + tn;
    {
        int r = tid >> 4, d0 = tid & 15;
        x1q[r][d0] = ws[OFF_X1Q + ((size_t)pair*N + ntile*16 + r)*D + d0];
        if (tid < 16) {
            int nn = ntile*16 + tid;
            ka[tid]  = ws[OFF_KVEC + a*N + nn];
            bea[tid] = ws[OFF_BETA + a*N + nn];
            xs1[tid] = ws[OFF_XS1 + (size_t)pair*N + nn];
        }
    }
    float acc = 0.f, accT = 0.f;
    const float* IKrow = ws + OFF_A + ((size_t)a*N + n)*N;
    for (int mt = 0; mt < 32; ++mt) {
        __syncthreads();
        int r = tid >> 4, d0 = tid & 15;
        x2t[r][d0] = ws[OFF_X1 + ((size_t)b*N + mt*16 + r)*D + d0];
        if (tid < 16) {
            int mmm = mt*16 + tid;
            kb[tid]  = ws[OFF_KVEC + b*N + mmm];
            beb[tid] = ws[OFF_BETA + b*N + mmm];
            xs2[tid] = ws[OFF_XS2 + (size_t)pair*N + mmm];
        }
        __syncthreads();
        float dot = 0.f;
        #pragma unroll
        for (int d = 0; d < D; ++d) dot += x1q[tn][d] * x2t[tm][d];
        float maha = 2.f*dot + xs1[tn] + xs2[tm];
        float Lv = __expf(ka[tn] + kb[tm] + maha);
        acc += bea[tn] * Lv * beb[tm];
        if (a == b) accT += IKrow[mt*16 + tm] * Lv;
    }
    red[tid] = acc; __syncthreads();
    for (int o = 128; o > 0; o >>= 1) { if (tid < o) red[tid] += red[tid+o]; __syncthreads(); }
    if (tid == 0) ws[OFF_SPART + bid] = red[0];
    if (a == b) {
        __syncthreads();
        red[tid] = accT; __syncthreads();
        for (int o = 128; o > 0; o >>= 1) { if (tid < o) red[tid] += red[tid+o]; __syncthreads(); }
        if (tid == 0) ws[OFF_TPART + a*32 + ntile] = red[0];
    }
}

// ---------- 8. finalize ----------
__global__ __launch_bounds__(256) void k_final(float* __restrict__ ws, const float* __restrict__ s,
                                               const float* __restrict__ os, float* __restrict__ out) {
    int tid = threadIdx.x;  // 256
    __shared__ float red[256];
    __shared__ float Msh[E], Vsh[E][D], cov[D][E+1];
    __shared__ float Sm[16][17], Si[16][17];

    for (int e = 0; e < E; ++e) {
        float p = 0.f;
        for (int n = tid; n < N; n += 256) p += ws[OFF_LB + e*N + n];
        red[tid] = p; __syncthreads();
        for (int o = 128; o > 0; o >>= 1) { if (tid < o) red[tid] += red[tid+o]; __syncthreads(); }
        if (tid == 0) Msh[e] = ws[OFF_C + e] * red[0];
        __syncthreads();
    }
    if (tid < E*D) {
        int e = tid / D, d = tid % D;
        float acc = 0.f;
        for (int n = 0; n < N; ++n)
            acc += ws[OFF_TIL + ((size_t)e*N + n)*D + d] * ws[OFF_LB + e*N + n];
        Vsh[e][d] = ws[OFF_C + e] * acc;
    }
    __syncthreads();

    if (tid < E*E) {
        int a = tid / E, bb = tid % E;
        float acc = 0.f;
        for (int q = 0; q < 32; ++q) acc += ws[OFF_SPART + (size_t)tid*32 + q];
        if (a == bb) {
            float tr = 0.f;
            for (int q = 0; q < 32; ++q) tr += ws[OFF_TPART + a*32 + q];
            acc -= tr;
        }
        acc *= ws[OFF_ISDR + tid];
        if (a == bb) acc += os[a];
        float v = acc - Msh[a]*Msh[bb];
        v *= ws[OFF_YSTD + a] * ws[OFF_YSTD + bb];
        out[E + tid] = v;                                // S
    }
    if (tid < E) out[tid] = Msh[tid]*ws[OFF_YSTD + tid] + ws[OFF_YMEAN + tid];  // Mout

    if (tid < D*E) {
        int d = tid / E, e = tid % E;
        float acc = 0.f;
        for (int k = 0; k < D; ++k) acc += ws[OFF_SSM + d*D + k] * Vsh[e][k];
        cov[d][e] = acc * ws[OFF_XSTD + d] * ws[OFF_YSTD + e];
    }
    int i = tid >> 4, j = tid & 15;
    Sm[i][j] = s[i*D + j];
    Si[i][j] = (i==j) ? 1.f : 0.f;
    __syncthreads();
    for (int k = 0; k < D; ++k) {
        float p   = Sm[k][k];
        float fik = Sm[i][k];
        float skj = Sm[k][j];
        float ikj = Si[k][j];
        __syncthreads();
        if (i == k) { Sm[k][j] = skj/p; Si[k][j] = ikj/p; }
        else        { float f = fik/p; Sm[i][j] -= f*skj; Si[i][j] -= f*ikj; }
        __syncthreads();
    }
    if (tid < D*E) {
        int d = tid / E, e = tid % E;
        float acc = 0.f;
        for (int k = 0; k < D; ++k) acc += Si[d][k] * cov[k][e];
        out[E + E*E + d*E + e] = acc;                    // Vout
    }
}

extern "C" void kernel_launch(void* const* d_in, const int* in_sizes, int n_in,
                              void* d_out, int out_size, void* d_ws, size_t ws_size,
                              hipStream_t stream) {
    const float* X     = (const float*)d_in[0];
    const float* Y     = (const float*)d_in[1];
    const float* m     = (const float*)d_in[2];
    const float* s     = (const float*)d_in[3];
    const float* ls    = (const float*)d_in[4];
    const float* os    = (const float*)d_in[5];
    const float* noise = (const float*)d_in[6];
    float* ws  = (float*)d_ws;
    float* out = (float*)d_out;

    k_prep  <<<1,    512, 0, stream>>>(X, Y, m, s, ws);
    k_buildA<<<E*64, 256, 0, stream>>>(ws, ls, os, noise);
    for (int kk = 0; kk < 8; ++kk) {
        int k0 = kk*64;
        k_diag64<<<E, 64, 0, stream>>>(ws, k0);
        int nb = 7 - kk;
        if (nb > 0) {
            k_panelmul<<<E*nb, 256, 0, stream>>>(ws, k0);
            k_trail<<<E*nb*(nb+1)/2, 256, 0, stream>>>(ws, k0);
        }
    }
    for (int d = 1; d < 8; ++d)
        k_tinv_off<<<E*(8-d), 256, 0, stream>>>(ws, d);
    k_syrk <<<E*36,      256, 0, stream>>>(ws);
    k_beta <<<E*2,       256, 0, stream>>>(ws);
    k_B    <<<E,         256, 0, stream>>>(ws, ls, os);
    k_R    <<<E*E,       256, 0, stream>>>(ws, ls);
    k_point<<<E*N/256,   256, 0, stream>>>(ws, ls, os);
    k_x1q  <<<E*E*N/256, 256, 0, stream>>>(ws);
    k_S    <<<E*E*32,    256, 0, stream>>>(ws);
    k_final<<<1,         256, 0, stream>>>(ws, s, os, out);
}